// Round 7
// baseline (6797.425 us; speedup 1.0000x reference)
//
#include <hip/hip_runtime.h>
#include <hip/hip_fp16.h>

#define B_   64
#define T_   512
#define DINc 512
#define D_   512
#define NWG  8
#define JS   64   // output columns per workgroup in scan

typedef _Float16 half8 __attribute__((ext_vector_type(8)));
typedef _Float16 half4 __attribute__((ext_vector_type(4)));
typedef float   floatx4 __attribute__((ext_vector_type(4)));
typedef unsigned uintx4 __attribute__((ext_vector_type(4)));

#define WAITV(N) asm volatile("s_waitcnt vmcnt(" #N ")" ::: "memory")
#define WAITL()  asm volatile("s_waitcnt lgkmcnt(0)" ::: "memory")
#define SCB()    __builtin_amdgcn_sched_barrier(0)
#define RBAR()   do { SCB(); __builtin_amdgcn_s_barrier(); SCB(); } while (0)

// ---------------- X convert + transpose: Xh[m][k] = (f16) X[b][t][k], m = t*64+b ----------------
__global__ __launch_bounds__(256) void k_cvtX(const float* __restrict__ X, _Float16* __restrict__ Xh) {
    int idx = blockIdx.x * 256 + threadIdx.x;
    int m  = idx >> 6;
    int k8 = idx & 63;
    int b = m & 63, t = m >> 6;
    const float* src = X + ((size_t)(b * T_ + t)) * DINc + k8 * 8;
    float4 f0 = *(const float4*)(src);
    float4 f1 = *(const float4*)(src + 4);
    half8 h;
    h[0] = (_Float16)f0.x; h[1] = (_Float16)f0.y; h[2] = (_Float16)f0.z; h[3] = (_Float16)f0.w;
    h[4] = (_Float16)f1.x; h[5] = (_Float16)f1.y; h[6] = (_Float16)f1.z; h[7] = (_Float16)f1.w;
    *(half8*)(Xh + (size_t)m * DINc + k8 * 8) = h;
}

// ---------------- generic 3-matrix transpose + convert: Mt[g][n][k] = (f16) M_g[k][n] ----------------
__global__ __launch_bounds__(256) void k_cvtW(const float* __restrict__ M0, const float* __restrict__ M1,
                                              const float* __restrict__ M2, _Float16* __restrict__ Mt) {
    __shared__ float tile[64][65];
    int g = blockIdx.z;
    const float* W = (g == 0) ? M0 : ((g == 1) ? M1 : M2);
    int n0 = blockIdx.x * 64, k0 = blockIdx.y * 64;
    int c = threadIdx.x & 63, r4 = threadIdx.x >> 6;
#pragma unroll
    for (int i = 0; i < 16; ++i) {
        int k = r4 + i * 4;
        tile[k][c] = W[(size_t)(k0 + k) * D_ + n0 + c];
    }
    __syncthreads();
    _Float16* out = Mt + (size_t)g * D_ * DINc;
#pragma unroll
    for (int i = 0; i < 16; ++i) {
        int n = r4 + i * 4;
        out[(size_t)(n0 + n) * DINc + k0 + c] = (_Float16)tile[c][n];
    }
}

// ---------------- mask transpose: maskT[t][b] = (float) mask[b][t] ----------------
__global__ __launch_bounds__(256) void k_cvtM(const int* __restrict__ mask, float* __restrict__ maskT) {
    int idx = blockIdx.x * 256 + threadIdx.x;   // 32768
    int t = idx >> 6, b = idx & 63;
    maskT[idx] = (float)mask[(size_t)b * T_ + t];
}

// ---- input projections: xprojT[g][t][n][b] = (Xh[m] @ W_g)[n] + b_g[n], m=t*64+b (f16) ----
__global__ __launch_bounds__(256) void k_gemm(const _Float16* __restrict__ Xh, const _Float16* __restrict__ Wt,
                                              const float* __restrict__ bz, const float* __restrict__ br,
                                              const float* __restrict__ bh, _Float16* __restrict__ xprojT) {
    __shared__ _Float16 As[128 * 32];
    __shared__ _Float16 Bs[128 * 32];
    int g = blockIdx.z;
    const _Float16* Wg = Wt + (size_t)g * 512 * 512;
    const float* bias = (g == 0) ? bz : ((g == 1) ? br : bh);
    _Float16* out = xprojT + (size_t)g * 16777216;
    int mb = blockIdx.x * 128, nb = blockIdx.y * 128;
    int tid = threadIdx.x, l = tid & 63, w = tid >> 6;
    int wr = w >> 1, wc = w & 1;
    int lr = l & 15, lg = l >> 4;

    floatx4 acc[4][4] = {};

    int ga0 = tid, ga1 = tid + 256;
    int ra0 = ga0 >> 2, ca0 = (ga0 & 3) * 8;
    int ra1 = ga1 >> 2, ca1 = (ga1 & 3) * 8;

    uint4 pa0, pa1, pb0, pb1;
    pa0 = *(const uint4*)(Xh + (size_t)(mb + ra0) * 512 + ca0);
    pa1 = *(const uint4*)(Xh + (size_t)(mb + ra1) * 512 + ca1);
    pb0 = *(const uint4*)(Wg + (size_t)(nb + ra0) * 512 + ca0);
    pb1 = *(const uint4*)(Wg + (size_t)(nb + ra1) * 512 + ca1);

    for (int kt = 0; kt < 16; ++kt) {
        __syncthreads();
        *(uint4*)(&As[ga0 * 8]) = pa0;
        *(uint4*)(&As[ga1 * 8]) = pa1;
        *(uint4*)(&Bs[ga0 * 8]) = pb0;
        *(uint4*)(&Bs[ga1 * 8]) = pb1;
        __syncthreads();
        if (kt < 15) {
            int kb = (kt + 1) * 32;
            pa0 = *(const uint4*)(Xh + (size_t)(mb + ra0) * 512 + kb + ca0);
            pa1 = *(const uint4*)(Xh + (size_t)(mb + ra1) * 512 + kb + ca1);
            pb0 = *(const uint4*)(Wg + (size_t)(nb + ra0) * 512 + kb + ca0);
            pb1 = *(const uint4*)(Wg + (size_t)(nb + ra1) * 512 + kb + ca1);
        }
        half8 af[4], bf[4];
#pragma unroll
        for (int mi = 0; mi < 4; mi++) af[mi] = *(const half8*)(&As[(wr * 64 + mi * 16 + lr) * 32 + lg * 8]);
#pragma unroll
        for (int ni = 0; ni < 4; ni++) bf[ni] = *(const half8*)(&Bs[(wc * 64 + ni * 16 + lr) * 32 + lg * 8]);
#pragma unroll
        for (int mi = 0; mi < 4; mi++)
#pragma unroll
            for (int ni = 0; ni < 4; ni++)
                acc[mi][ni] = __builtin_amdgcn_mfma_f32_16x16x32_f16(af[mi], bf[ni], acc[mi][ni], 0, 0, 0);
    }

#pragma unroll
    for (int ni = 0; ni < 4; ni++) {
        int col = nb + wc * 64 + ni * 16 + lr;
        float bv = bias[col];
#pragma unroll
        for (int mi = 0; mi < 4; mi++) {
            int row = mb + wr * 64 + mi * 16 + lg * 4;
            int tt = row >> 6, bb = row & 63;
            half4 hv;
#pragma unroll
            for (int i = 0; i < 4; i++) hv[i] = (_Float16)(acc[mi][ni][i] + bv);
            *(half4*)(out + (size_t)tt * 32768 + (size_t)col * 64 + bb) = hv;
        }
    }
}

// -------- agent-scope (device-coherent) primitives — PROVEN path (R2/R6) --------
__device__ __forceinline__ void st_agent(unsigned long long* p, unsigned long long v) {
    __hip_atomic_store(p, v, __ATOMIC_RELAXED, __HIP_MEMORY_SCOPE_AGENT);
}
__device__ __forceinline__ unsigned ld_flag(const unsigned* p) {
    return __hip_atomic_load(p, __ATOMIC_RELAXED, __HIP_MEMORY_SCOPE_AGENT);
}
__device__ __forceinline__ void st_flag(unsigned* p, unsigned v) {
    __hip_atomic_store(p, v, __ATOMIC_RELAXED, __HIP_MEMORY_SCOPE_AGENT);
}
__device__ __forceinline__ uintx4 ld16_agent(const void* p) {
    uintx4 r;
    asm volatile("global_load_dwordx4 %0, %1, off sc0 sc1" : "=v"(r) : "v"(p) : "memory");
    return r;
}

// pack 4 fp32 (4 rows, 1 col) -> 8B row-major unit (1 row, 4 cols), 2-round butterfly (R6-proven)
__device__ __forceinline__ unsigned long long pack_quad(const float v4[4], int lr) {
    unsigned long long unit = 0;
    int j = lr & 3;
#pragma unroll
    for (int i = 0; i < 4; i++) {
        _Float16 hv = (_Float16)v4[i];
        unsigned int v = (unsigned int)__builtin_bit_cast(unsigned short, hv);
        unsigned int o1 = __shfl_xor(v, 1, 64);
        unsigned int pair = (lr & 1) ? (o1 | (v << 16)) : (v | (o1 << 16));
        unsigned int q2 = __shfl_xor(pair, 2, 64);
        unsigned long long u = (lr & 2) ? ((unsigned long long)q2 | ((unsigned long long)pair << 32))
                                        : ((unsigned long long)pair | ((unsigned long long)q2 << 32));
        if (i == j) unit = u;
    }
    return unit;
}

// ---------------- recurrent scan: 8 WGs x 512 threads, each owns JS=64 columns ----------------
__global__ __launch_bounds__(512) void k_scan(const _Float16* __restrict__ Ut,      // [3][n][k] f16
                                              const float* __restrict__ maskT,
                                              const _Float16* __restrict__ xprojT,
                                              unsigned long long* __restrict__ hbuf,   // [2][64][128] u64
                                              unsigned long long* __restrict__ rhbuf,  // [2][64][128] u64
                                              unsigned* __restrict__ fh, unsigned* __restrict__ fr,
                                              float* __restrict__ out) {
    __shared__ __align__(16) char Lds[163840];   // Uz 64KB | Ur 64KB | Stg 32KB = 160KB
    char* LdsB = Lds;
    char* StgB = Lds + 131072;
    int tid = threadIdx.x, l = tid & 63, w = tid >> 6;
    int lr = l & 15, lg = l >> 4;
    int nt  = w >> 1;                 // N-tile 0..3 (16 cols each)
    int mt2 = w & 1;                  // M-tile pair selector
    int m0 = mt2 * 16, m1 = m0 + 32;  // wave's two 16-row M-tiles
    int slot = blockIdx.x;
    int jsb = slot * JS;

    // ---- stage Uz, Ur into LDS (transposed f16 input; add XOR swizzle) ----
    for (int c = tid; c < 2 * 64 * 64; c += 512) {   // 16B chunks
        int g   = c >> 12;
        int n   = (c >> 6) & 63;
        int k16 = c & 63;
        uintx4 v = *(const uintx4*)(Ut + (size_t)g * 262144 + (size_t)(jsb + n) * 512 + k16 * 8);
        *(uintx4*)(LdsB + g * 65536 + n * 1024 + ((k16 * 16) ^ ((n & 7) << 4))) = v;
    }
    // ---- preload U_h fragments into registers (static across t) ----
    half8 uhf[16];
    {
        const _Float16* UtH = Ut + (size_t)2 * 262144;
        int ncol = jsb + nt * 16 + lr;
#pragma unroll
        for (int j = 0; j < 16; j++)
            uhf[j] = *(const half8*)(UtH + (size_t)ncol * 512 + j * 32 + lg * 8);
    }
    __syncthreads();

    const char* UBz = LdsB + (nt * 16 + lr) * 1024;          // Uz B-row base
    const char* UBr = UBz + 65536;                            // Ur B-row base
    const int swz = (lr & 7) << 4;
    const int r0s = (m0 + lr) * 512;                          // staging A-row byte bases
    const int r1s = (m1 + lr) * 512;

    int colg = jsb + nt * 16 + lr;            // this thread's C-col (global hidden index)
    int row0 = m0 + lg * 4;                   // first of 4 C-rows, M-tile 0
    int row1 = m1 + lg * 4;                   // first of 4 C-rows, M-tile 1

    float h4[2][4]  = {};
    float hm4[2][4] = {};

    const int punit0 = (m0 + lg * 4 + (lr & 3)) * 128 + ((jsb + nt * 16) >> 2) + ((lr >> 2) & 3);
    const int punit1 = (m1 + lg * 4 + (lr & 3)) * 128 + ((jsb + nt * 16) >> 2) + ((lr >> 2) & 3);

    const int gr0  = w * 8 + (l >> 5);        // gather row base (wave covers rows w*8..w*8+7)
    const int gcol = (l & 31) * 16;           // byte offset within 512B half-row

    const _Float16* xzB = xprojT + (size_t)colg * 64;
    const _Float16* xrB = xzB + (size_t)16777216;
    const _Float16* xhB = xrB + (size_t)16777216;

    // ---------------- step 0: hm = 0, pure local ----------------
    {
        half4 xz0a = *(const half4*)(xzB + row0), xz0b = *(const half4*)(xzB + row1);
        half4 xh0a = *(const half4*)(xhB + row0), xh0b = *(const half4*)(xhB + row1);
        float4 m0a = *(const float4*)(maskT + row0), m0b = *(const float4*)(maskT + row1);
#pragma unroll
        for (int i = 0; i < 4; i++) {
            float za = 1.f / (1.f + __expf(-(float)xz0a[i]));
            float zb = 1.f / (1.f + __expf(-(float)xz0b[i]));
            h4[0][i] = (1.f - za) * tanhf((float)xh0a[i]);
            h4[1][i] = (1.f - zb) * tanhf((float)xh0b[i]);
            hm4[0][i] = ((float)m0a[i]) * h4[0][i];
            hm4[1][i] = ((float)m0b[i]) * h4[1][i];
        }
        st_agent(hbuf + punit0, pack_quad(hm4[0], lr));
        st_agent(hbuf + punit1, pack_quad(hm4[1], lr));
        WAITV(0);
        __syncthreads();
        if (tid == 0) st_flag(fh + slot * 16, 1u);
    }

    for (int t = 1; t < T_; ++t) {
        const char* hmG = (const char*)(hbuf + ((t - 1) & 1) * 8192);
        const char* rhG = (const char*)(rhbuf + (t & 1) * 8192);
        unsigned long long* rhW = rhbuf + (t & 1) * 8192;
        unsigned long long* hW  = hbuf + (t & 1) * 8192;

        // issue this step's x loads early (fly during the flag wait)
        const _Float16* xzT = xzB + (size_t)t * 32768;
        const _Float16* xrT = xrB + (size_t)t * 32768;
        const _Float16* xhT = xhB + (size_t)t * 32768;
        half4 xzp0 = *(const half4*)(xzT + row0), xzp1 = *(const half4*)(xzT + row1);
        half4 xrp0 = *(const half4*)(xrT + row0), xrp1 = *(const half4*)(xrT + row1);
        half4 xhp0 = *(const half4*)(xhT + row0), xhp1 = *(const half4*)(xhT + row1);
        float4 mva = *(const float4*)(maskT + (size_t)t * 64 + row0);
        float4 mvb = *(const float4*)(maskT + (size_t)t * 64 + row1);

        // ================= phase 1: z, r =================
        if (w == 0) {
            for (;;) {
                unsigned v = (l < NWG) ? ld_flag(fh + l * 16) : (unsigned)t;
                if (__all(v >= (unsigned)t)) break;
            }
        }
        __syncthreads();   // drains x loads + broadcasts "flags seen"

        floatx4 accz0 = {}, accz1 = {}, accr0 = {}, accr1 = {};
        {
            uintx4 gg[8];
#pragma unroll
            for (int it = 0; it < 4; ++it)
                gg[it] = ld16_agent(hmG + (gr0 + it * 2) * 1024 + gcol);
#pragma unroll
            for (int it = 0; it < 4; ++it)
                gg[4 + it] = ld16_agent(hmG + (gr0 + it * 2) * 1024 + 512 + gcol);
            WAITV(4); SCB();
#pragma unroll
            for (int it = 0; it < 4; ++it) {
                int r = gr0 + it * 2;
                *(uintx4*)(StgB + r * 512 + (gcol ^ ((r & 7) << 4))) = gg[it];
            }
            WAITL(); RBAR();
#pragma unroll
            for (int j = 0; j < 8; ++j) {          // K half 1
                int kbyte = j * 64 + lg * 16;
                half8 a0 = *(const half8*)(StgB + r0s + (kbyte ^ swz));
                half8 a1 = *(const half8*)(StgB + r1s + (kbyte ^ swz));
                int ub = kbyte ^ swz;
                half8 bz = *(const half8*)(UBz + ub);
                half8 br = *(const half8*)(UBr + ub);
                accz0 = __builtin_amdgcn_mfma_f32_16x16x32_f16(a0, bz, accz0, 0, 0, 0);
                accr0 = __builtin_amdgcn_mfma_f32_16x16x32_f16(a0, br, accr0, 0, 0, 0);
                accz1 = __builtin_amdgcn_mfma_f32_16x16x32_f16(a1, bz, accz1, 0, 0, 0);
                accr1 = __builtin_amdgcn_mfma_f32_16x16x32_f16(a1, br, accr1, 0, 0, 0);
            }
            RBAR();                                 // all waves done reading half 1
            WAITV(0); SCB();
#pragma unroll
            for (int it = 0; it < 4; ++it) {
                int r = gr0 + it * 2;
                *(uintx4*)(StgB + r * 512 + (gcol ^ ((r & 7) << 4))) = gg[4 + it];
            }
            WAITL(); RBAR();
#pragma unroll
            for (int j = 0; j < 8; ++j) {          // K half 2
                int kbyte = j * 64 + lg * 16;
                half8 a0 = *(const half8*)(StgB + r0s + (kbyte ^ swz));
                half8 a1 = *(const half8*)(StgB + r1s + (kbyte ^ swz));
                int ub = (512 + kbyte) ^ swz;
                half8 bz = *(const half8*)(UBz + ub);
                half8 br = *(const half8*)(UBr + ub);
                accz0 = __builtin_amdgcn_mfma_f32_16x16x32_f16(a0, bz, accz0, 0, 0, 0);
                accr0 = __builtin_amdgcn_mfma_f32_16x16x32_f16(a0, br, accr0, 0, 0, 0);
                accz1 = __builtin_amdgcn_mfma_f32_16x16x32_f16(a1, bz, accz1, 0, 0, 0);
                accr1 = __builtin_amdgcn_mfma_f32_16x16x32_f16(a1, br, accr1, 0, 0, 0);
            }
        }
        float z4[2][4], rh4[2][4];
#pragma unroll
        for (int i = 0; i < 4; i++) {
            z4[0][i] = 1.f / (1.f + __expf(-((float)xzp0[i] + accz0[i])));
            z4[1][i] = 1.f / (1.f + __expf(-((float)xzp1[i] + accz1[i])));
            rh4[0][i] = (1.f / (1.f + __expf(-((float)xrp0[i] + accr0[i])))) * hm4[0][i];
            rh4[1][i] = (1.f / (1.f + __expf(-((float)xrp1[i] + accr1[i])))) * hm4[1][i];
        }
        st_agent(rhW + punit0, pack_quad(rh4[0], lr));
        st_agent(rhW + punit1, pack_quad(rh4[1], lr));
        WAITV(0);
        __syncthreads();
        if (tid == 0) st_flag(fr + slot * 16, (unsigned)t);

        // ================= phase 2: candidate + update =================
        if (w == 0) {
            for (;;) {
                unsigned v = (l < NWG) ? ld_flag(fr + l * 16) : (unsigned)t;
                if (__all(v >= (unsigned)t)) break;
            }
        }
        __syncthreads();

        floatx4 acch0 = {}, acch1 = {};
        {
            uintx4 gg[8];
#pragma unroll
            for (int it = 0; it < 4; ++it)
                gg[it] = ld16_agent(rhG + (gr0 + it * 2) * 1024 + gcol);
#pragma unroll
            for (int it = 0; it < 4; ++it)
                gg[4 + it] = ld16_agent(rhG + (gr0 + it * 2) * 1024 + 512 + gcol);
            WAITV(4); SCB();
#pragma unroll
            for (int it = 0; it < 4; ++it) {
                int r = gr0 + it * 2;
                *(uintx4*)(StgB + r * 512 + (gcol ^ ((r & 7) << 4))) = gg[it];
            }
            WAITL(); RBAR();
#pragma unroll
            for (int j = 0; j < 8; ++j) {          // K half 1
                int kbyte = j * 64 + lg * 16;
                half8 a0 = *(const half8*)(StgB + r0s + (kbyte ^ swz));
                half8 a1 = *(const half8*)(StgB + r1s + (kbyte ^ swz));
                acch0 = __builtin_amdgcn_mfma_f32_16x16x32_f16(a0, uhf[j], acch0, 0, 0, 0);
                acch1 = __builtin_amdgcn_mfma_f32_16x16x32_f16(a1, uhf[j], acch1, 0, 0, 0);
            }
            RBAR();
            WAITV(0); SCB();
#pragma unroll
            for (int it = 0; it < 4; ++it) {
                int r = gr0 + it * 2;
                *(uintx4*)(StgB + r * 512 + (gcol ^ ((r & 7) << 4))) = gg[4 + it];
            }
            WAITL(); RBAR();
#pragma unroll
            for (int j = 0; j < 8; ++j) {          // K half 2
                int kbyte = j * 64 + lg * 16;
                half8 a0 = *(const half8*)(StgB + r0s + (kbyte ^ swz));
                half8 a1 = *(const half8*)(StgB + r1s + (kbyte ^ swz));
                acch0 = __builtin_amdgcn_mfma_f32_16x16x32_f16(a0, uhf[8 + j], acch0, 0, 0, 0);
                acch1 = __builtin_amdgcn_mfma_f32_16x16x32_f16(a1, uhf[8 + j], acch1, 0, 0, 0);
            }
        }
#pragma unroll
        for (int i = 0; i < 4; i++) {
            float hha = tanhf((float)xhp0[i] + acch0[i]);
            float hhb = tanhf((float)xhp1[i] + acch1[i]);
            h4[0][i] = z4[0][i] * hm4[0][i] + (1.f - z4[0][i]) * hha;
            h4[1][i] = z4[1][i] * hm4[1][i] + (1.f - z4[1][i]) * hhb;
            hm4[0][i] = ((float)mva[i]) * h4[0][i];
            hm4[1][i] = ((float)mvb[i]) * h4[1][i];
        }
        st_agent(hW + punit0, pack_quad(hm4[0], lr));
        st_agent(hW + punit1, pack_quad(hm4[1], lr));
        WAITV(0);
        __syncthreads();
        if (tid == 0) st_flag(fh + slot * 16, (unsigned)(t + 1));
    }

#pragma unroll
    for (int i = 0; i < 4; i++) {
        out[(size_t)(row0 + i) * 512 + colg] = h4[0][i];
        out[(size_t)(row1 + i) * 512 + colg] = h4[1][i];
    }
}

extern "C" void kernel_launch(void* const* d_in, const int* in_sizes, int n_in,
                              void* d_out, int out_size, void* d_ws, size_t ws_size,
                              hipStream_t stream) {
    (void)in_sizes; (void)n_in; (void)out_size; (void)ws_size;
    const float* X  = (const float*)d_in[0];
    const float* Wz = (const float*)d_in[1];
    const float* Uz = (const float*)d_in[2];
    const float* bz = (const float*)d_in[3];
    const float* Wr = (const float*)d_in[4];
    const float* Ur = (const float*)d_in[5];
    const float* br = (const float*)d_in[6];
    const float* Wh = (const float*)d_in[7];
    const float* Uh = (const float*)d_in[8];
    const float* bh = (const float*)d_in[9];
    const int* mask = (const int*)d_in[10];
    float* out = (float*)d_out;

    char* ws = (char*)d_ws;
    unsigned* fh = (unsigned*)ws;                                    // flags (8 slots, 64B stride)
    unsigned* fr = (unsigned*)(ws + 1024);
    unsigned long long* hbuf  = (unsigned long long*)(ws + 8192);              // 128KB [2][64][128]
    unsigned long long* rhbuf = (unsigned long long*)(ws + 8192 + 131072);     // 128KB
    _Float16* Xh     = (_Float16*)(ws + 8192 + 2 * 131072);                    // 32MB
    _Float16* Wt     = (_Float16*)(ws + 8192 + 2 * 131072 + 33554432);         // 1.5MB
    _Float16* Ut     = (_Float16*)(ws + 8192 + 2 * 131072 + 33554432 + 1572864);           // 1.5MB
    _Float16* xprojT = (_Float16*)(ws + 8192 + 2 * 131072 + 33554432 + 2 * 1572864);       // 96MB
    float*    maskT  = (float*)(ws + 8192 + 2 * 131072 + 33554432 + 2 * 1572864 + 100663296); // 128KB

    hipMemsetAsync(ws, 0, 8192, stream);
    hipLaunchKernelGGL(k_cvtX, dim3(8192), dim3(256), 0, stream, X, Xh);
    hipLaunchKernelGGL(k_cvtW, dim3(8, 8, 3), dim3(256), 0, stream, Wz, Wr, Wh, Wt);
    hipLaunchKernelGGL(k_cvtW, dim3(8, 8, 3), dim3(256), 0, stream, Uz, Ur, Uh, Ut);
    hipLaunchKernelGGL(k_cvtM, dim3(128), dim3(256), 0, stream, mask, maskT);
    hipLaunchKernelGGL(k_gemm, dim3(256, 4, 3), dim3(256), 0, stream, Xh, Wt, bz, br, bh, xprojT);
    hipLaunchKernelGGL(k_scan, dim3(NWG), dim3(512), 0, stream, Ut, maskT, xprojT,
                       hbuf, rhbuf, fh, fr, out);
}

// Round 8
// 5137.564 us; speedup vs baseline: 1.3231x; 1.3231x over previous
//
#include <hip/hip_runtime.h>
#include <hip/hip_fp16.h>

#define B_   64
#define T_   512
#define DINc 512
#define D_   512
#define NWG  16
#define JS   32   // output columns per workgroup in scan

typedef _Float16 half8 __attribute__((ext_vector_type(8)));
typedef _Float16 half4 __attribute__((ext_vector_type(4)));
typedef float   floatx4 __attribute__((ext_vector_type(4)));
typedef unsigned uintx4 __attribute__((ext_vector_type(4)));

#define WAITV0() asm volatile("s_waitcnt vmcnt(0)" ::: "memory")
#define SCB()    __builtin_amdgcn_sched_barrier(0)

// ---------------- X convert + transpose: Xh[m][k] = (f16) X[b][t][k], m = t*64+b ----------------
__global__ __launch_bounds__(256) void k_cvtX(const float* __restrict__ X, _Float16* __restrict__ Xh) {
    int idx = blockIdx.x * 256 + threadIdx.x;
    int m  = idx >> 6;
    int k8 = idx & 63;
    int b = m & 63, t = m >> 6;
    const float* src = X + ((size_t)(b * T_ + t)) * DINc + k8 * 8;
    float4 f0 = *(const float4*)(src);
    float4 f1 = *(const float4*)(src + 4);
    half8 h;
    h[0] = (_Float16)f0.x; h[1] = (_Float16)f0.y; h[2] = (_Float16)f0.z; h[3] = (_Float16)f0.w;
    h[4] = (_Float16)f1.x; h[5] = (_Float16)f1.y; h[6] = (_Float16)f1.z; h[7] = (_Float16)f1.w;
    *(half8*)(Xh + (size_t)m * DINc + k8 * 8) = h;
}

// ---------------- generic 3-matrix transpose + convert: Mt[g][n][k] = (f16) M_g[k][n] ----------------
__global__ __launch_bounds__(256) void k_cvtW(const float* __restrict__ M0, const float* __restrict__ M1,
                                              const float* __restrict__ M2, _Float16* __restrict__ Mt) {
    __shared__ float tile[64][65];
    int g = blockIdx.z;
    const float* W = (g == 0) ? M0 : ((g == 1) ? M1 : M2);
    int n0 = blockIdx.x * 64, k0 = blockIdx.y * 64;
    int c = threadIdx.x & 63, r4 = threadIdx.x >> 6;
#pragma unroll
    for (int i = 0; i < 16; ++i) {
        int k = r4 + i * 4;
        tile[k][c] = W[(size_t)(k0 + k) * D_ + n0 + c];
    }
    __syncthreads();
    _Float16* out = Mt + (size_t)g * D_ * DINc;
#pragma unroll
    for (int i = 0; i < 16; ++i) {
        int n = r4 + i * 4;
        out[(size_t)(n0 + n) * DINc + k0 + c] = (_Float16)tile[c][n];
    }
}

// ---------------- mask transpose: maskT[t][b] = (float) mask[b][t] ----------------
__global__ __launch_bounds__(256) void k_cvtM(const int* __restrict__ mask, float* __restrict__ maskT) {
    int idx = blockIdx.x * 256 + threadIdx.x;   // 32768
    int t = idx >> 6, b = idx & 63;
    maskT[idx] = (float)mask[(size_t)b * T_ + t];
}

// ---- input projections: xprojT[g][t][n][b] = (Xh[m] @ W_g)[n] + b_g[n], m=t*64+b (f16) ----
__global__ __launch_bounds__(256) void k_gemm(const _Float16* __restrict__ Xh, const _Float16* __restrict__ Wt,
                                              const float* __restrict__ bz, const float* __restrict__ br,
                                              const float* __restrict__ bh, _Float16* __restrict__ xprojT) {
    __shared__ _Float16 As[128 * 32];
    __shared__ _Float16 Bs[128 * 32];
    int g = blockIdx.z;
    const _Float16* Wg = Wt + (size_t)g * 512 * 512;
    const float* bias = (g == 0) ? bz : ((g == 1) ? br : bh);
    _Float16* out = xprojT + (size_t)g * 16777216;
    int mb = blockIdx.x * 128, nb = blockIdx.y * 128;
    int tid = threadIdx.x, l = tid & 63, w = tid >> 6;
    int wr = w >> 1, wc = w & 1;
    int lr = l & 15, lg = l >> 4;

    floatx4 acc[4][4] = {};

    int ga0 = tid, ga1 = tid + 256;
    int ra0 = ga0 >> 2, ca0 = (ga0 & 3) * 8;
    int ra1 = ga1 >> 2, ca1 = (ga1 & 3) * 8;

    uint4 pa0, pa1, pb0, pb1;
    pa0 = *(const uint4*)(Xh + (size_t)(mb + ra0) * 512 + ca0);
    pa1 = *(const uint4*)(Xh + (size_t)(mb + ra1) * 512 + ca1);
    pb0 = *(const uint4*)(Wg + (size_t)(nb + ra0) * 512 + ca0);
    pb1 = *(const uint4*)(Wg + (size_t)(nb + ra1) * 512 + ca1);

    for (int kt = 0; kt < 16; ++kt) {
        __syncthreads();
        *(uint4*)(&As[ga0 * 8]) = pa0;
        *(uint4*)(&As[ga1 * 8]) = pa1;
        *(uint4*)(&Bs[ga0 * 8]) = pb0;
        *(uint4*)(&Bs[ga1 * 8]) = pb1;
        __syncthreads();
        if (kt < 15) {
            int kb = (kt + 1) * 32;
            pa0 = *(const uint4*)(Xh + (size_t)(mb + ra0) * 512 + kb + ca0);
            pa1 = *(const uint4*)(Xh + (size_t)(mb + ra1) * 512 + kb + ca1);
            pb0 = *(const uint4*)(Wg + (size_t)(nb + ra0) * 512 + kb + ca0);
            pb1 = *(const uint4*)(Wg + (size_t)(nb + ra1) * 512 + kb + ca1);
        }
        half8 af[4], bf[4];
#pragma unroll
        for (int mi = 0; mi < 4; mi++) af[mi] = *(const half8*)(&As[(wr * 64 + mi * 16 + lr) * 32 + lg * 8]);
#pragma unroll
        for (int ni = 0; ni < 4; ni++) bf[ni] = *(const half8*)(&Bs[(wc * 64 + ni * 16 + lr) * 32 + lg * 8]);
#pragma unroll
        for (int mi = 0; mi < 4; mi++)
#pragma unroll
            for (int ni = 0; ni < 4; ni++)
                acc[mi][ni] = __builtin_amdgcn_mfma_f32_16x16x32_f16(af[mi], bf[ni], acc[mi][ni], 0, 0, 0);
    }

#pragma unroll
    for (int ni = 0; ni < 4; ni++) {
        int col = nb + wc * 64 + ni * 16 + lr;
        float bv = bias[col];
#pragma unroll
        for (int mi = 0; mi < 4; mi++) {
            int row = mb + wr * 64 + mi * 16 + lg * 4;
            int tt = row >> 6, bb = row & 63;
            half4 hv;
#pragma unroll
            for (int i = 0; i < 4; i++) hv[i] = (_Float16)(acc[mi][ni][i] + bv);
            *(half4*)(out + (size_t)tt * 32768 + (size_t)col * 64 + bb) = hv;
        }
    }
}

// -------- agent-scope (device-coherent) primitives — PROVEN path (R2/R6) --------
__device__ __forceinline__ void st_agent(unsigned long long* p, unsigned long long v) {
    __hip_atomic_store(p, v, __ATOMIC_RELAXED, __HIP_MEMORY_SCOPE_AGENT);
}
__device__ __forceinline__ uintx4 ld16_agent(const void* p) {
    uintx4 r;
    asm volatile("global_load_dwordx4 %0, %1, off sc0 sc1" : "=v"(r) : "v"(p) : "memory");
    return r;
}
// chunk (16B = 2x 8B publish units) is valid iff neither u64 is the 0xFF.. sentinel
__device__ __forceinline__ bool chunk_valid(uintx4 v) {
    return ((v[0] & v[1]) != 0xFFFFFFFFu) && ((v[2] & v[3]) != 0xFFFFFFFFu);
}

// pack 4 fp32 (4 rows, 1 col) -> 8B row-major unit (1 row, 4 cols), 2-round butterfly (R6-proven)
__device__ __forceinline__ unsigned long long pack_quad(const float v4[4], int lr) {
    unsigned long long unit = 0;
    int j = lr & 3;
#pragma unroll
    for (int i = 0; i < 4; i++) {
        _Float16 hv = (_Float16)v4[i];
        unsigned int v = (unsigned int)__builtin_bit_cast(unsigned short, hv);
        unsigned int o1 = __shfl_xor(v, 1, 64);
        unsigned int pair = (lr & 1) ? (o1 | (v << 16)) : (v | (o1 << 16));
        unsigned int q2 = __shfl_xor(pair, 2, 64);
        unsigned long long u = (lr & 2) ? ((unsigned long long)q2 | ((unsigned long long)pair << 32))
                                        : ((unsigned long long)pair | ((unsigned long long)q2 << 32));
        if (i == j) unit = u;
    }
    return unit;
}

// ---------------- recurrent scan: 16 WGs x 512 threads, each owns JS=32 columns ----------------
// Sync = sentinel-poll on the exchange data itself (no flags). Buffers pre-poisoned to 0xFF.
// Poison schedule (race-free by construction):
//   step t phase 1: gather-success of hm_{t-1}  ==> all WGs done phase 2 of t-1 ==> poison rhbuf[(t-1)&1]
//   step t phase 2: gather-success of rh_t      ==> all WGs done phase 1 of t   ==> poison hbuf[(t-1)&1]
// Each poisoned buffer is republished one step later; vmcnt(0) drains in between order same-address stores.
__global__ __launch_bounds__(512, 2) void k_scan(const _Float16* __restrict__ Ut,      // [3][n][k] f16
                                                 const float* __restrict__ maskT,
                                                 const _Float16* __restrict__ xprojT,
                                                 unsigned long long* __restrict__ hbuf,   // [2][64][128] u64
                                                 unsigned long long* __restrict__ rhbuf,  // [2][64][128] u64
                                                 float* __restrict__ out) {
    __shared__ __align__(16) _Float16 Ulds[2 * JS * 512];   // 64KB: Uz,Ur [n][k] swizzled
    __shared__ __align__(16) _Float16 Stg[64 * 512];        // 64KB: exchange staging, swizzled
    char* StgB = (char*)Stg;
    int tid = threadIdx.x, l = tid & 63, w = tid >> 6;
    int lr = l & 15, lg = l >> 4;
    int mt = w >> 1, nt = w & 1;              // wave's (M,N) 16x16 tile
    int slot = blockIdx.x;
    int jsb = slot * JS;

    // ---- stage Uz, Ur into LDS (already transposed f16; add XOR swizzle) ----
    for (int c = tid; c < 2 * JS * 64; c += 512) {     // 16B chunks: 2 gates x 32 n x 64 chunks
        int g  = c >> 11;
        int n  = (c >> 6) & 31;
        int k16 = c & 63;
        uintx4 v = *(const uintx4*)(Ut + (size_t)g * 262144 + (size_t)(jsb + n) * 512 + k16 * 8);
        *(uintx4*)((char*)Ulds + g * 32768 + n * 1024 + ((k16 * 16) ^ ((n & 7) << 4))) = v;
    }
    // ---- preload U_h fragments into registers (static across t) ----
    half8 uhf[16];
    {
        const _Float16* UtH = Ut + (size_t)2 * 262144;
        int ncol = jsb + nt * 16 + lr;
#pragma unroll
        for (int j = 0; j < 16; j++)
            uhf[j] = *(const half8*)(UtH + (size_t)ncol * 512 + j * 32 + lg * 8);
    }
    __syncthreads();

    const char* UB = (const char*)Ulds + (nt * 16 + lr) * 1024;  // B-row base for Uz (Ur at +32KB)
    const int swz = (lr & 7) << 4;

    int row0 = mt * 16 + lg * 4;              // this thread's 4 C-rows (batch)
    int colg = jsb + nt * 16 + lr;            // this thread's C-col (global hidden index)

    float h4[4]  = {0.f, 0.f, 0.f, 0.f};
    float hm4[4] = {0.f, 0.f, 0.f, 0.f};

    const int punit = (mt * 16 + lg * 4 + (lr & 3)) * 128 + ((jsb + nt * 16) >> 2) + ((lr >> 2) & 3);
    const char* SB = StgB + (mt * 16 + lr) * 1024;    // A-frag row base in staging

    const _Float16* xzB = xprojT + (size_t)colg * 64 + row0;
    const _Float16* xrB = xzB + (size_t)16777216;
    const _Float16* xhB = xrB + (size_t)16777216;

    // ---------------- step 0: hm = 0, pure local ----------------
    {
        half4 xz0 = *(const half4*)(xzB);
        half4 xh0 = *(const half4*)(xhB);
        float4 m0 = *(const float4*)(maskT + row0);
#pragma unroll
        for (int i = 0; i < 4; i++) {
            float z  = 1.f / (1.f + __expf(-(float)xz0[i]));
            float hh = tanhf((float)xh0[i]);
            h4[i]  = (1.f - z) * hh;
            hm4[i] = ((float)m0[i]) * h4[i];
        }
        st_agent(hbuf + punit, pack_quad(hm4, lr));   // parity 0; consumers data-poll
    }

    for (int t = 1; t < T_; ++t) {
        const char* hmG = (const char*)(hbuf + ((t - 1) & 1) * 8192);
        unsigned long long* rhPsn = rhbuf + ((t - 1) & 1) * 8192;   // poison target, phase 1
        unsigned long long* hPsn  = hbuf  + ((t - 1) & 1) * 8192;   // poison target, phase 2
        unsigned long long* rhW   = rhbuf + (t & 1) * 8192;
        unsigned long long* hW    = hbuf  + (t & 1) * 8192;
        const char* rhG = (const char*)rhW;

        // issue this step's x loads early (drained by first gather WAITV0)
        half4 xzp = *(const half4*)(xzB + (size_t)t * 32768);
        half4 xrp = *(const half4*)(xrB + (size_t)t * 32768);
        half4 xhp = *(const half4*)(xhB + (size_t)t * 32768);
        float4 mv = *(const float4*)(maskT + (size_t)t * 64 + row0);

        // ================= phase 1: z, r =================
        uintx4 gg[8];
        for (;;) {   // data-poll gather: rows w*8..w*8+7, 16B coalesced sc1 loads
#pragma unroll
            for (int it = 0; it < 8; ++it)
                gg[it] = ld16_agent(hmG + (w * 8 + it) * 1024 + l * 16);
            WAITV0(); SCB();
            bool ok = true;
#pragma unroll
            for (int it = 0; it < 8; ++it) ok = ok && chunk_valid(gg[it]);
            if (__all(ok)) break;
        }
        st_agent(rhPsn + punit, ~0ull);   // poison rh[(t-1)&1]: all WGs proven past phase 2 of t-1
        __syncthreads();                  // all waves: prev staging reads done + gathers complete
#pragma unroll
        for (int it = 0; it < 8; ++it)
            *(uintx4*)(StgB + (w * 8 + it) * 1024 + ((l * 16) ^ (it << 4))) = gg[it];
        __syncthreads();
        half8 af[16];
#pragma unroll
        for (int j = 0; j < 16; j++)
            af[j] = *(const half8*)(SB + ((j * 64 + lg * 16) ^ swz));
        floatx4 accz = {0.f, 0.f, 0.f, 0.f}, accr = {0.f, 0.f, 0.f, 0.f};
#pragma unroll
        for (int j = 0; j < 16; j++) {
            int boff = (j * 64 + lg * 16) ^ swz;
            half8 bz8 = *(const half8*)(UB + boff);
            half8 br8 = *(const half8*)(UB + 32768 + boff);
            accz = __builtin_amdgcn_mfma_f32_16x16x32_f16(af[j], bz8, accz, 0, 0, 0);
            accr = __builtin_amdgcn_mfma_f32_16x16x32_f16(af[j], br8, accr, 0, 0, 0);
        }
        float z4[4], rh4[4];
#pragma unroll
        for (int i = 0; i < 4; i++) {
            float zz = 1.f / (1.f + __expf(-((float)xzp[i] + accz[i])));
            float rr = 1.f / (1.f + __expf(-((float)xrp[i] + accr[i])));
            z4[i]  = zz;
            rh4[i] = rr * hm4[i];
        }
        st_agent(rhW + punit, pack_quad(rh4, lr));   // publish rh_t (no drain, no flag)

        // ================= phase 2: candidate + update =================
        uintx4 gg2[8];
        for (;;) {
#pragma unroll
            for (int it = 0; it < 8; ++it)
                gg2[it] = ld16_agent(rhG + (w * 8 + it) * 1024 + l * 16);
            WAITV0(); SCB();
            bool ok = true;
#pragma unroll
            for (int it = 0; it < 8; ++it) ok = ok && chunk_valid(gg2[it]);
            if (__all(ok)) break;
        }
        st_agent(hPsn + punit, ~0ull);   // poison h[(t-1)&1]: all WGs proven past phase 1 of t
        __syncthreads();
#pragma unroll
        for (int it = 0; it < 8; ++it)
            *(uintx4*)(StgB + (w * 8 + it) * 1024 + ((l * 16) ^ (it << 4))) = gg2[it];
        __syncthreads();
        half8 af2[16];
#pragma unroll
        for (int j = 0; j < 16; j++)
            af2[j] = *(const half8*)(SB + ((j * 64 + lg * 16) ^ swz));
        floatx4 acch0 = {0.f, 0.f, 0.f, 0.f}, acch1 = {0.f, 0.f, 0.f, 0.f};
#pragma unroll
        for (int j = 0; j < 16; j += 2) {
            acch0 = __builtin_amdgcn_mfma_f32_16x16x32_f16(af2[j],     uhf[j],     acch0, 0, 0, 0);
            acch1 = __builtin_amdgcn_mfma_f32_16x16x32_f16(af2[j + 1], uhf[j + 1], acch1, 0, 0, 0);
        }
#pragma unroll
        for (int i = 0; i < 4; i++) {
            float hh = tanhf((float)xhp[i] + acch0[i] + acch1[i]);
            h4[i]  = z4[i] * hm4[i] + (1.f - z4[i]) * hh;
            hm4[i] = ((float)mv[i]) * h4[i];
        }
        st_agent(hW + punit, pack_quad(hm4, lr));    // publish hm_t
    }

#pragma unroll
    for (int i = 0; i < 4; i++)
        out[(size_t)(row0 + i) * 512 + colg] = h4[i];
}

extern "C" void kernel_launch(void* const* d_in, const int* in_sizes, int n_in,
                              void* d_out, int out_size, void* d_ws, size_t ws_size,
                              hipStream_t stream) {
    (void)in_sizes; (void)n_in; (void)out_size; (void)ws_size;
    const float* X  = (const float*)d_in[0];
    const float* Wz = (const float*)d_in[1];
    const float* Uz = (const float*)d_in[2];
    const float* bz = (const float*)d_in[3];
    const float* Wr = (const float*)d_in[4];
    const float* Ur = (const float*)d_in[5];
    const float* br = (const float*)d_in[6];
    const float* Wh = (const float*)d_in[7];
    const float* Uh = (const float*)d_in[8];
    const float* bh = (const float*)d_in[9];
    const int* mask = (const int*)d_in[10];
    float* out = (float*)d_out;

    char* ws = (char*)d_ws;
    unsigned long long* hbuf  = (unsigned long long*)(ws + 8192);              // 128KB [2][64][128]
    unsigned long long* rhbuf = (unsigned long long*)(ws + 8192 + 131072);     // 128KB
    _Float16* Xh     = (_Float16*)(ws + 8192 + 2 * 131072);                    // 32MB
    _Float16* Wt     = (_Float16*)(ws + 8192 + 2 * 131072 + 33554432);         // 1.5MB
    _Float16* Ut     = (_Float16*)(ws + 8192 + 2 * 131072 + 33554432 + 1572864);           // 1.5MB
    _Float16* xprojT = (_Float16*)(ws + 8192 + 2 * 131072 + 33554432 + 2 * 1572864);       // 96MB
    float*    maskT  = (float*)(ws + 8192 + 2 * 131072 + 33554432 + 2 * 1572864 + 100663296); // 128KB

    // pre-poison exchange region every launch (graph-replay determinism)
    hipMemsetAsync(ws + 8192, 0xFF, 2 * 131072, stream);
    hipLaunchKernelGGL(k_cvtX, dim3(8192), dim3(256), 0, stream, X, Xh);
    hipLaunchKernelGGL(k_cvtW, dim3(8, 8, 3), dim3(256), 0, stream, Wz, Wr, Wh, Wt);
    hipLaunchKernelGGL(k_cvtW, dim3(8, 8, 3), dim3(256), 0, stream, Uz, Ur, Uh, Ut);
    hipLaunchKernelGGL(k_cvtM, dim3(128), dim3(256), 0, stream, mask, maskT);
    hipLaunchKernelGGL(k_gemm, dim3(256, 4, 3), dim3(256), 0, stream, Xh, Wt, bz, br, bh, xprojT);
    hipLaunchKernelGGL(k_scan, dim3(NWG), dim3(512), 0, stream, Ut, maskT, xprojT,
                       hbuf, rhbuf, out);
}

// Round 9
// 3758.361 us; speedup vs baseline: 1.8086x; 1.3670x over previous
//
#include <hip/hip_runtime.h>
#include <hip/hip_fp16.h>

#define B_   64
#define T_   512
#define DINc 512
#define D_   512
#define NWG  16
#define JS   32   // output columns per workgroup in scan

typedef _Float16 half8 __attribute__((ext_vector_type(8)));
typedef _Float16 half4 __attribute__((ext_vector_type(4)));
typedef float   floatx4 __attribute__((ext_vector_type(4)));
typedef unsigned uintx4 __attribute__((ext_vector_type(4)));

#define WAITV(N) asm volatile("s_waitcnt vmcnt(" #N ")" ::: "memory")
#define SCB()    __builtin_amdgcn_sched_barrier(0)

// ---------------- X convert + transpose: Xh[m][k] = (f16) X[b][t][k], m = t*64+b ----------------
__global__ __launch_bounds__(256) void k_cvtX(const float* __restrict__ X, _Float16* __restrict__ Xh) {
    int idx = blockIdx.x * 256 + threadIdx.x;
    int m  = idx >> 6;
    int k8 = idx & 63;
    int b = m & 63, t = m >> 6;
    const float* src = X + ((size_t)(b * T_ + t)) * DINc + k8 * 8;
    float4 f0 = *(const float4*)(src);
    float4 f1 = *(const float4*)(src + 4);
    half8 h;
    h[0] = (_Float16)f0.x; h[1] = (_Float16)f0.y; h[2] = (_Float16)f0.z; h[3] = (_Float16)f0.w;
    h[4] = (_Float16)f1.x; h[5] = (_Float16)f1.y; h[6] = (_Float16)f1.z; h[7] = (_Float16)f1.w;
    *(half8*)(Xh + (size_t)m * DINc + k8 * 8) = h;
}

// ---------------- generic 3-matrix transpose + convert: Mt[g][n][k] = (f16) M_g[k][n] ----------------
__global__ __launch_bounds__(256) void k_cvtW(const float* __restrict__ M0, const float* __restrict__ M1,
                                              const float* __restrict__ M2, _Float16* __restrict__ Mt) {
    __shared__ float tile[64][65];
    int g = blockIdx.z;
    const float* W = (g == 0) ? M0 : ((g == 1) ? M1 : M2);
    int n0 = blockIdx.x * 64, k0 = blockIdx.y * 64;
    int c = threadIdx.x & 63, r4 = threadIdx.x >> 6;
#pragma unroll
    for (int i = 0; i < 16; ++i) {
        int k = r4 + i * 4;
        tile[k][c] = W[(size_t)(k0 + k) * D_ + n0 + c];
    }
    __syncthreads();
    _Float16* out = Mt + (size_t)g * D_ * DINc;
#pragma unroll
    for (int i = 0; i < 16; ++i) {
        int n = r4 + i * 4;
        out[(size_t)(n0 + n) * DINc + k0 + c] = (_Float16)tile[c][n];
    }
}

// ---------------- mask transpose: maskT[t][b] = (float) mask[b][t] ----------------
__global__ __launch_bounds__(256) void k_cvtM(const int* __restrict__ mask, float* __restrict__ maskT) {
    int idx = blockIdx.x * 256 + threadIdx.x;   // 32768
    int t = idx >> 6, b = idx & 63;
    maskT[idx] = (float)mask[(size_t)b * T_ + t];
}

// ---- input projections: xprojT[g][t][n][b] = (Xh[m] @ W_g)[n] + b_g[n], m=t*64+b (f16) ----
__global__ __launch_bounds__(256) void k_gemm(const _Float16* __restrict__ Xh, const _Float16* __restrict__ Wt,
                                              const float* __restrict__ bz, const float* __restrict__ br,
                                              const float* __restrict__ bh, _Float16* __restrict__ xprojT) {
    __shared__ _Float16 As[128 * 32];
    __shared__ _Float16 Bs[128 * 32];
    int g = blockIdx.z;
    const _Float16* Wg = Wt + (size_t)g * 512 * 512;
    const float* bias = (g == 0) ? bz : ((g == 1) ? br : bh);
    _Float16* out = xprojT + (size_t)g * 16777216;
    int mb = blockIdx.x * 128, nb = blockIdx.y * 128;
    int tid = threadIdx.x, l = tid & 63, w = tid >> 6;
    int wr = w >> 1, wc = w & 1;
    int lr = l & 15, lg = l >> 4;

    floatx4 acc[4][4] = {};

    int ga0 = tid, ga1 = tid + 256;
    int ra0 = ga0 >> 2, ca0 = (ga0 & 3) * 8;
    int ra1 = ga1 >> 2, ca1 = (ga1 & 3) * 8;

    uint4 pa0, pa1, pb0, pb1;
    pa0 = *(const uint4*)(Xh + (size_t)(mb + ra0) * 512 + ca0);
    pa1 = *(const uint4*)(Xh + (size_t)(mb + ra1) * 512 + ca1);
    pb0 = *(const uint4*)(Wg + (size_t)(nb + ra0) * 512 + ca0);
    pb1 = *(const uint4*)(Wg + (size_t)(nb + ra1) * 512 + ca1);

    for (int kt = 0; kt < 16; ++kt) {
        __syncthreads();
        *(uint4*)(&As[ga0 * 8]) = pa0;
        *(uint4*)(&As[ga1 * 8]) = pa1;
        *(uint4*)(&Bs[ga0 * 8]) = pb0;
        *(uint4*)(&Bs[ga1 * 8]) = pb1;
        __syncthreads();
        if (kt < 15) {
            int kb = (kt + 1) * 32;
            pa0 = *(const uint4*)(Xh + (size_t)(mb + ra0) * 512 + kb + ca0);
            pa1 = *(const uint4*)(Xh + (size_t)(mb + ra1) * 512 + kb + ca1);
            pb0 = *(const uint4*)(Wg + (size_t)(nb + ra0) * 512 + kb + ca0);
            pb1 = *(const uint4*)(Wg + (size_t)(nb + ra1) * 512 + kb + ca1);
        }
        half8 af[4], bf[4];
#pragma unroll
        for (int mi = 0; mi < 4; mi++) af[mi] = *(const half8*)(&As[(wr * 64 + mi * 16 + lr) * 32 + lg * 8]);
#pragma unroll
        for (int ni = 0; ni < 4; ni++) bf[ni] = *(const half8*)(&Bs[(wc * 64 + ni * 16 + lr) * 32 + lg * 8]);
#pragma unroll
        for (int mi = 0; mi < 4; mi++)
#pragma unroll
            for (int ni = 0; ni < 4; ni++)
                acc[mi][ni] = __builtin_amdgcn_mfma_f32_16x16x32_f16(af[mi], bf[ni], acc[mi][ni], 0, 0, 0);
    }

#pragma unroll
    for (int ni = 0; ni < 4; ni++) {
        int col = nb + wc * 64 + ni * 16 + lr;
        float bv = bias[col];
#pragma unroll
        for (int mi = 0; mi < 4; mi++) {
            int row = mb + wr * 64 + mi * 16 + lg * 4;
            int tt = row >> 6, bb = row & 63;
            half4 hv;
#pragma unroll
            for (int i = 0; i < 4; i++) hv[i] = (_Float16)(acc[mi][ni][i] + bv);
            *(half4*)(out + (size_t)tt * 32768 + (size_t)col * 64 + bb) = hv;
        }
    }
}

// -------- agent-scope (device-coherent) primitives — PROVEN path (R2/R6) --------
__device__ __forceinline__ void st_agent(unsigned long long* p, unsigned long long v) {
    __hip_atomic_store(p, v, __ATOMIC_RELAXED, __HIP_MEMORY_SCOPE_AGENT);
}
__device__ __forceinline__ unsigned ld_flag(const unsigned* p) {
    return __hip_atomic_load(p, __ATOMIC_RELAXED, __HIP_MEMORY_SCOPE_AGENT);
}
__device__ __forceinline__ void st_flag(unsigned* p, unsigned v) {
    __hip_atomic_store(p, v, __ATOMIC_RELAXED, __HIP_MEMORY_SCOPE_AGENT);
}
__device__ __forceinline__ uintx4 ld16_agent(const void* p) {
    uintx4 r;
    asm volatile("global_load_dwordx4 %0, %1, off sc0 sc1" : "=v"(r) : "v"(p) : "memory");
    return r;
}

// pack 4 fp32 (4 rows, 1 col) -> 8B row-major unit (1 row, 4 cols), 2-round butterfly (R6-proven)
__device__ __forceinline__ unsigned long long pack_quad(const float v4[4], int lr) {
    unsigned long long unit = 0;
    int j = lr & 3;
#pragma unroll
    for (int i = 0; i < 4; i++) {
        _Float16 hv = (_Float16)v4[i];
        unsigned int v = (unsigned int)__builtin_bit_cast(unsigned short, hv);
        unsigned int o1 = __shfl_xor(v, 1, 64);
        unsigned int pair = (lr & 1) ? (o1 | (v << 16)) : (v | (o1 << 16));
        unsigned int q2 = __shfl_xor(pair, 2, 64);
        unsigned long long u = (lr & 2) ? ((unsigned long long)q2 | ((unsigned long long)pair << 32))
                                        : ((unsigned long long)pair | ((unsigned long long)q2 << 32));
        if (i == j) unit = u;
    }
    return unit;
}

// every-wave poll of 128 per-wave flags (lanes 0..63 -> flags 0..63, +64 -> 64..127)
__device__ __forceinline__ void poll_flags(const unsigned* f, unsigned need, int l) {
    for (;;) {
        unsigned v0 = ld_flag(f + l * 16);
        unsigned v1 = ld_flag(f + (64 + l) * 16);
        if (__all(v0 >= need && v1 >= need)) break;
    }
    SCB();
}

// ---------------- recurrent scan: 16 WGs x 512 threads, each owns JS=32 columns ----------------
// Sync skeleton = R6 (agent-relaxed data + monotonic epoch flags), with per-WAVE flags
// (publish-early, no publisher syncthreads) and every-wave independent polling.
__global__ __launch_bounds__(512) void k_scan(const _Float16* __restrict__ Ut,      // [3][n][k] f16
                                              const float* __restrict__ maskT,
                                              const _Float16* __restrict__ xprojT,
                                              unsigned long long* __restrict__ hbuf,   // [2][64][128] u64
                                              unsigned long long* __restrict__ rhbuf,  // [2][64][128] u64
                                              unsigned* __restrict__ fh, unsigned* __restrict__ fr,
                                              float* __restrict__ out) {
    __shared__ __align__(16) _Float16 Ulds[2 * JS * 512];   // 64KB: Uz,Ur [n][k] swizzled
    __shared__ __align__(16) _Float16 Stg[64 * 512];        // 64KB: exchange staging, swizzled
    char* StgB = (char*)Stg;
    int tid = threadIdx.x, l = tid & 63, w = tid >> 6;
    int lr = l & 15, lg = l >> 4;
    int mt = w >> 1, nt = w & 1;              // wave's (M,N) 16x16 tile
    int slot = blockIdx.x;
    int jsb = slot * JS;
    const int fidx = slot * 8 + w;            // this wave's flag index (x16 u32 = 64B stride)

    // ---- stage Uz, Ur into LDS (already transposed f16; add XOR swizzle) ----
    for (int c = tid; c < 2 * JS * 64; c += 512) {     // 16B chunks: 2 gates x 32 n x 64 chunks
        int g  = c >> 11;
        int n  = (c >> 6) & 31;
        int k16 = c & 63;
        uintx4 v = *(const uintx4*)(Ut + (size_t)g * 262144 + (size_t)(jsb + n) * 512 + k16 * 8);
        *(uintx4*)((char*)Ulds + g * 32768 + n * 1024 + ((k16 * 16) ^ ((n & 7) << 4))) = v;
    }
    // ---- preload U_h fragments into registers (static across t) ----
    half8 uhf[16];
    {
        const _Float16* UtH = Ut + (size_t)2 * 262144;
        int ncol = jsb + nt * 16 + lr;
#pragma unroll
        for (int j = 0; j < 16; j++)
            uhf[j] = *(const half8*)(UtH + (size_t)ncol * 512 + j * 32 + lg * 8);
    }
    __syncthreads();

    const char* UB = (const char*)Ulds + (nt * 16 + lr) * 1024;  // B-row base for Uz (Ur at +32KB)
    const int swz = (lr & 7) << 4;

    int row0 = mt * 16 + lg * 4;              // this thread's 4 C-rows (batch)
    int colg = jsb + nt * 16 + lr;            // this thread's C-col (global hidden index)

    float h4[4]  = {0.f, 0.f, 0.f, 0.f};
    float hm4[4] = {0.f, 0.f, 0.f, 0.f};

    const int punit = (mt * 16 + lg * 4 + (lr & 3)) * 128 + ((jsb + nt * 16) >> 2) + ((lr >> 2) & 3);
    const char* SB = StgB + (mt * 16 + lr) * 1024;    // A-frag row base in staging

    const _Float16* xzB = xprojT + (size_t)colg * 64 + row0;
    const _Float16* xrB = xzB + (size_t)16777216;
    const _Float16* xhB = xrB + (size_t)16777216;

    // ---------------- step 0: hm = 0, pure local ----------------
    {
        half4 xz0 = *(const half4*)(xzB);
        half4 xh0 = *(const half4*)(xhB);
        float4 m0 = *(const float4*)(maskT + row0);
#pragma unroll
        for (int i = 0; i < 4; i++) {
            float z  = __builtin_amdgcn_rcpf(1.f + __expf(-(float)xz0[i]));
            float hh = tanhf((float)xh0[i]);
            h4[i]  = (1.f - z) * hh;
            hm4[i] = ((float)m0[i]) * h4[i];
        }
        st_agent(hbuf + punit, pack_quad(hm4, lr));   // parity 0
        WAITV(0);
        if (l == 0) st_flag(fh + fidx * 16, 1u);      // per-wave flag, publish-early
    }

    for (int t = 1; t < T_; ++t) {
        const char* hmG = (const char*)(hbuf + ((t - 1) & 1) * 8192);
        unsigned long long* rhW = rhbuf + (t & 1) * 8192;
        unsigned long long* hW  = hbuf  + (t & 1) * 8192;
        const char* rhG = (const char*)rhW;

        // issue this step's x loads early (counted by the staging vmcnt waits)
        half4 xzp = *(const half4*)(xzB + (size_t)t * 32768);
        half4 xrp = *(const half4*)(xrB + (size_t)t * 32768);
        half4 xhp = *(const half4*)(xhB + (size_t)t * 32768);
        float4 mv = *(const float4*)(maskT + (size_t)t * 64 + row0);

        // ================= phase 1: r (then z off-path) =================
        __syncthreads();                 // all waves done reading Stg from prev phase
        poll_flags(fh, (unsigned)t, l);  // every wave polls independently
        {
            uintx4 gg[8];
#pragma unroll
            for (int it = 0; it < 8; ++it)
                gg[it] = ld16_agent(hmG + (w * 8 + it) * 1024 + l * 16);
            WAITV(4); SCB();
#pragma unroll
            for (int it = 0; it < 4; ++it)
                *(uintx4*)(StgB + (w * 8 + it) * 1024 + ((l * 16) ^ (it << 4))) = gg[it];
            WAITV(0); SCB();
#pragma unroll
            for (int it = 4; it < 8; ++it)
                *(uintx4*)(StgB + (w * 8 + it) * 1024 + ((l * 16) ^ (it << 4))) = gg[it];
        }
        __syncthreads();
        half8 af[16];
#pragma unroll
        for (int j = 0; j < 16; j++)
            af[j] = *(const half8*)(SB + ((j * 64 + lg * 16) ^ swz));
        // --- r first: its result gates the next rendezvous ---
        floatx4 accr = {0.f, 0.f, 0.f, 0.f};
#pragma unroll
        for (int j = 0; j < 16; j++) {
            int boff = (j * 64 + lg * 16) ^ swz;
            half8 br8 = *(const half8*)(UB + 32768 + boff);
            accr = __builtin_amdgcn_mfma_f32_16x16x32_f16(af[j], br8, accr, 0, 0, 0);
        }
        float rh4[4];
#pragma unroll
        for (int i = 0; i < 4; i++) {
            float rr = __builtin_amdgcn_rcpf(1.f + __expf(-((float)xrp[i] + accr[i])));
            rh4[i] = rr * hm4[i];
        }
        st_agent(rhW + punit, pack_quad(rh4, lr));
        WAITV(0);
        if (l == 0) st_flag(fr + fidx * 16, (unsigned)t);
        // --- z while rh propagates to peers ---
        floatx4 accz = {0.f, 0.f, 0.f, 0.f};
#pragma unroll
        for (int j = 0; j < 16; j++) {
            int boff = (j * 64 + lg * 16) ^ swz;
            half8 bz8 = *(const half8*)(UB + boff);
            accz = __builtin_amdgcn_mfma_f32_16x16x32_f16(af[j], bz8, accz, 0, 0, 0);
        }
        float z4[4];
#pragma unroll
        for (int i = 0; i < 4; i++)
            z4[i] = __builtin_amdgcn_rcpf(1.f + __expf(-((float)xzp[i] + accz[i])));

        // ================= phase 2: candidate + update =================
        __syncthreads();                 // all waves done reading Stg (af)
        poll_flags(fr, (unsigned)t, l);
        {
            uintx4 gg[8];
#pragma unroll
            for (int it = 0; it < 8; ++it)
                gg[it] = ld16_agent(rhG + (w * 8 + it) * 1024 + l * 16);
            WAITV(4); SCB();
#pragma unroll
            for (int it = 0; it < 4; ++it)
                *(uintx4*)(StgB + (w * 8 + it) * 1024 + ((l * 16) ^ (it << 4))) = gg[it];
            WAITV(0); SCB();
#pragma unroll
            for (int it = 4; it < 8; ++it)
                *(uintx4*)(StgB + (w * 8 + it) * 1024 + ((l * 16) ^ (it << 4))) = gg[it];
        }
        __syncthreads();
        half8 af2[16];
#pragma unroll
        for (int j = 0; j < 16; j++)
            af2[j] = *(const half8*)(SB + ((j * 64 + lg * 16) ^ swz));
        floatx4 acch0 = {0.f, 0.f, 0.f, 0.f}, acch1 = {0.f, 0.f, 0.f, 0.f};
#pragma unroll
        for (int j = 0; j < 16; j += 2) {
            acch0 = __builtin_amdgcn_mfma_f32_16x16x32_f16(af2[j],     uhf[j],     acch0, 0, 0, 0);
            acch1 = __builtin_amdgcn_mfma_f32_16x16x32_f16(af2[j + 1], uhf[j + 1], acch1, 0, 0, 0);
        }
#pragma unroll
        for (int i = 0; i < 4; i++) {
            float hh = tanhf((float)xhp[i] + acch0[i] + acch1[i]);
            h4[i]  = z4[i] * hm4[i] + (1.f - z4[i]) * hh;
            hm4[i] = ((float)mv[i]) * h4[i];
        }
        st_agent(hW + punit, pack_quad(hm4, lr));
        WAITV(0);
        if (l == 0) st_flag(fh + fidx * 16, (unsigned)(t + 1));
    }

#pragma unroll
    for (int i = 0; i < 4; i++)
        out[(size_t)(row0 + i) * 512 + colg] = h4[i];
}

extern "C" void kernel_launch(void* const* d_in, const int* in_sizes, int n_in,
                              void* d_out, int out_size, void* d_ws, size_t ws_size,
                              hipStream_t stream) {
    (void)in_sizes; (void)n_in; (void)out_size; (void)ws_size;
    const float* X  = (const float*)d_in[0];
    const float* Wz = (const float*)d_in[1];
    const float* Uz = (const float*)d_in[2];
    const float* bz = (const float*)d_in[3];
    const float* Wr = (const float*)d_in[4];
    const float* Ur = (const float*)d_in[5];
    const float* br = (const float*)d_in[6];
    const float* Wh = (const float*)d_in[7];
    const float* Uh = (const float*)d_in[8];
    const float* bh = (const float*)d_in[9];
    const int* mask = (const int*)d_in[10];
    float* out = (float*)d_out;

    char* ws = (char*)d_ws;
    unsigned* fh = (unsigned*)ws;                                    // 8KB: 128 per-wave flags, 64B stride
    unsigned* fr = (unsigned*)(ws + 8192);                           // 8KB
    unsigned long long* hbuf  = (unsigned long long*)(ws + 16384);              // 128KB [2][64][128]
    unsigned long long* rhbuf = (unsigned long long*)(ws + 16384 + 131072);     // 128KB
    _Float16* Xh     = (_Float16*)(ws + 16384 + 2 * 131072);                    // 32MB
    _Float16* Wt     = (_Float16*)(ws + 16384 + 2 * 131072 + 33554432);         // 1.5MB
    _Float16* Ut     = (_Float16*)(ws + 16384 + 2 * 131072 + 33554432 + 1572864);           // 1.5MB
    _Float16* xprojT = (_Float16*)(ws + 16384 + 2 * 131072 + 33554432 + 2 * 1572864);       // 96MB
    float*    maskT  = (float*)(ws + 16384 + 2 * 131072 + 33554432 + 2 * 1572864 + 100663296); // 128KB

    hipMemsetAsync(ws, 0, 16384, stream);
    hipLaunchKernelGGL(k_cvtX, dim3(8192), dim3(256), 0, stream, X, Xh);
    hipLaunchKernelGGL(k_cvtW, dim3(8, 8, 3), dim3(256), 0, stream, Wz, Wr, Wh, Wt);
    hipLaunchKernelGGL(k_cvtW, dim3(8, 8, 3), dim3(256), 0, stream, Uz, Ur, Uh, Ut);
    hipLaunchKernelGGL(k_cvtM, dim3(128), dim3(256), 0, stream, mask, maskT);
    hipLaunchKernelGGL(k_gemm, dim3(256, 4, 3), dim3(256), 0, stream, Xh, Wt, bz, br, bh, xprojT);
    hipLaunchKernelGGL(k_scan, dim3(NWG), dim3(512), 0, stream, Ut, maskT, xprojT,
                       hbuf, rhbuf, fh, fr, out);
}